// Round 1
// baseline (45.790 us; speedup 1.0000x reference)
//
#include <hip/hip_runtime.h>

// FACoef: out[b] = sum_{i,j} coef[i,j] * S_{i+2}(b)^{j+1} / n^{i+j+2}
// where S_k(b) = sum of all entries of x_b^k  (k = 2,3,4), n = G*G.
// Key identity: sum(x^k) = 1^T x^k 1, computed via a row-vector chain:
//   u1 = 1^T x (column sums), u_{k} = u_{k-1} x, S_k = sum(u_k).
// O(B*G^2) instead of O(B*G^3); memory-bound: read x exactly once.

#define G 128

typedef float v4f __attribute__((ext_vector_type(4)));

__global__ __launch_bounds__(512, 4) void facoef_kernel(
    const float* __restrict__ x, const float* __restrict__ coef,
    float* __restrict__ out) {
  const int b = blockIdx.x;
  const int tid = threadIdx.x;
  const int cg = tid & 31;   // column group: cols [4*cg, 4*cg+3]
  const int rh = tid >> 5;   // row chunk:    rows [8*rh, 8*rh+7]

  __shared__ float part[16][128];  // per-rowchunk partials (lane-consecutive)
  __shared__ float u[128];         // current row-vector u_k
  __shared__ float Sp[3][2];       // S2,S3,S4 per-wave partials

  const float* xb = x + (size_t)b * (G * G);

  // Load this thread's 8x4 slice of x into registers (coalesced dwordx4).
  v4f xs[8];
#pragma unroll
  for (int r = 0; r < 8; ++r) {
    xs[r] = *(const v4f*)(xb + (rh * 8 + r) * G + cg * 4);
  }

  // ---- u1 = column sums ----
  v4f acc = xs[0];
#pragma unroll
  for (int r = 1; r < 8; ++r) acc += xs[r];
  *(v4f*)&part[rh][cg * 4] = acc;
  __syncthreads();

  if (tid < 128) {
    float s = 0.f;
#pragma unroll
    for (int h = 0; h < 16; ++h) s += part[h][tid];
    u[tid] = s;
  }
  __syncthreads();

  // ---- u2,u3 (stored) and S2,S3,S4 ----
  for (int k = 0; k < 3; ++k) {
    v4f a = {0.f, 0.f, 0.f, 0.f};
#pragma unroll
    for (int r = 0; r < 8; ++r) {
      float uv = u[rh * 8 + r];  // broadcast read
      a += uv * xs[r];
    }
    *(v4f*)&part[rh][cg * 4] = a;
    __syncthreads();

    if (tid < 128) {
      float s = 0.f;
#pragma unroll
      for (int h = 0; h < 16; ++h) s += part[h][tid];
      // wave-level sum over the 128 u-entries for S_{k+2}
      float t = s;
#pragma unroll
      for (int off = 32; off > 0; off >>= 1) t += __shfl_xor(t, off, 64);
      if ((tid & 63) == 0) Sp[k][tid >> 6] = t;
      if (k < 2) u[tid] = s;  // u_{k+2} feeds the next matvec
    }
    __syncthreads();
  }

  if (tid == 0) {
    double S[3];
#pragma unroll
    for (int k = 0; k < 3; ++k) S[k] = (double)Sp[k][0] + (double)Sp[k][1];
    const double n = (double)(G * G);
    double np[7];
    np[2] = n * n;
    np[3] = np[2] * n;
    np[4] = np[3] * n;
    np[5] = np[4] * n;
    np[6] = np[5] * n;
    double o = 0.0;
#pragma unroll
    for (int i = 0; i < 3; ++i) {
      double s1 = S[i], s2 = s1 * s1, s3 = s2 * s1;
      double sp[3] = {s1, s2, s3};
#pragma unroll
      for (int j = 0; j < 3; ++j) {
        o += (double)coef[i * 3 + j] * sp[j] / np[i + j + 2];
      }
    }
    out[b] = (float)o;
  }
}

extern "C" void kernel_launch(void* const* d_in, const int* in_sizes, int n_in,
                              void* d_out, int out_size, void* d_ws, size_t ws_size,
                              hipStream_t stream) {
  const float* x = (const float*)d_in[0];
  const float* coef = (const float*)d_in[1];
  float* out = (float*)d_out;
  const int batch = in_sizes[0] / (G * G);
  facoef_kernel<<<batch, 512, 0, stream>>>(x, coef, out);
}